// Round 14
// baseline (253.853 us; speedup 1.0000x reference)
//
#include <hip/hip_runtime.h>
#include <hip/hip_bf16.h>

// CoarseGraining: y[i,b] = heg[b] * sum_j exp(-beta[j,b] * d2(i,j)) * wrho[j]
// N = M = 8192, NB = 16, WIDTH = 32. Inputs float32, output float32.
// R11 155us -> R13 packed-f32 134us (busy 104.5us; ~75% of cycles = 32
// v_exp_f32/iter at ~12cyc on the quarter-rate trans pipe, in-order issue
// stalls behind it at ~2.5 waves/SIMD).
// R14: HYBRID exp — half the exps stay on the trans pipe (q=0,1), half move
// to a packed deg-4 polynomial exp2 on the full-rate VALU pipe (q=2,3):
// floor + 4x v_pk_fma_f32 Horner + v_ldexp. Two pipes run concurrently.
// Poly rel err ~1.4e-3 << 2.5e-2 threshold.
// Builtins: exp2 = __builtin_amdgcn_exp2f, log2 = __builtin_amdgcn_logf.

#define N_PTS 8192
#define M_PTS 8192
#define NBASIS 16
#define WIDTH 32

typedef float v2f __attribute__((ext_vector_type(2)));

__device__ __forceinline__ float exp2_hw(float x) { return __builtin_amdgcn_exp2f(x); }
__device__ __forceinline__ float log2_hw(float x) { return __builtin_amdgcn_logf(x); }

// Packed polynomial exp2 for z <= 0 (both lanes of the i-pair at once).
// exp2(z) = 2^floor(z) * p(frac(z)), p = Taylor deg-4 (rel err <= ~1.4e-3).
// Scalar ops (floor/cvt/ldexp) are full-rate; Horner is 4x v_pk_fma_f32.
__device__ __forceinline__ v2f exp2_poly(v2f z) {
    float z0 = fmaxf(z.x, -150.0f);
    float z1 = fmaxf(z.y, -150.0f);
    float n0 = floorf(z0), n1 = floorf(z1);
    v2f f = { z0 - n0, z1 - n1 };
    v2f p = (v2f)0.05550411f + f * (v2f)0.00961804f;
    p = (v2f)0.24022651f + f * p;
    p = (v2f)0.69314718f + f * p;
    p = (v2f)1.0f        + f * p;
    return (v2f){ ldexpf(p.x, (int)n0), ldexpf(p.y, (int)n1) };
}

__device__ __forceinline__ float fast_tanh(float z) {
    float a = fabsf(z);
    float t = __expf(-2.0f * a);
    float r = (1.0f - t) / (1.0f + t);
    return copysignf(r, z);
}

__device__ __forceinline__ float log_cosh_f(float x) {
    float a = fabsf(x);
    return a + __logf(1.0f + __expf(-2.0f * a)) - 0.6931471805599453f;
}

// ---------------- Stage 1: per-source-point quantities ----------------
// cw[j]        = (cx, cy, cz, wrho)
// bnq[q*N + j] = float4{ bn[j][4q..4q+3] }, bn = -log2(e)*beta (q-plane layout)
// hegf[0..15]  = log_cosh(embed(0))^1.5
__global__ __launch_bounds__(64)
void cg_prep(const float* __restrict__ rho,
             const float* __restrict__ gamma,
             const float* __restrict__ coords,
             const float* __restrict__ weights,
             const float* __restrict__ w1,
             const float* __restrict__ b1,
             const float* __restrict__ w2,
             const float* __restrict__ b2,
             float4* __restrict__ cw,
             float4* __restrict__ bnq,
             float* __restrict__ hegf)
{
    const float PI_F = 3.14159265358979323846f;
    const float LOG2E = 1.4426950408889634f;

    __shared__ float s_w1[WIDTH], s_b1[WIDTH], s_w2[WIDTH * NBASIS], s_b2[NBASIS];
    int t = threadIdx.x;
    if (t < WIDTH) { s_w1[t] = w1[t]; s_b1[t] = b1[t]; }
    if (t < NBASIS) s_b2[t] = b2[t];
    #pragma unroll
    for (int k = 0; k < 8; ++k) s_w2[t + 64 * k] = w2[t + 64 * k];
    __syncthreads();

    int j = blockIdx.x * 64 + t;
    {
        float r = rho[j];
        float g = gamma[j];
        const float c83 = 38.28312007948569f;              // 4*(3*pi^2)^(2/3)
        float r83 = exp2_hw(2.6666666667f * log2_hw(r));   // r^(8/3)
        float s2 = g / (c83 * r83);
        float x = __logf(s2 + 1e-4f);

        float emb[NBASIS];
        #pragma unroll
        for (int b = 0; b < NBASIS; ++b) emb[b] = s_b2[b];
        #pragma unroll 4
        for (int w = 0; w < WIDTH; ++w) {
            float h = fast_tanh(fmaf(x, s_w1[w], s_b1[w]));
            #pragma unroll
            for (int b = 0; b < NBASIS; ++b)
                emb[b] = fmaf(h, s_w2[w * NBASIS + b], emb[b]);
        }
        float pref = PI_F * exp2_hw(0.6666666667f * log2_hw(0.5f * r));
        float scale = -LOG2E * pref;
        #pragma unroll
        for (int q = 0; q < 4; ++q) {
            bnq[q * N_PTS + j] = make_float4(scale * log_cosh_f(emb[4 * q + 0]),
                                             scale * log_cosh_f(emb[4 * q + 1]),
                                             scale * log_cosh_f(emb[4 * q + 2]),
                                             scale * log_cosh_f(emb[4 * q + 3]));
        }

        cw[j] = make_float4(coords[j * 3 + 0],
                            coords[j * 3 + 1],
                            coords[j * 3 + 2],
                            weights[j] * r);
    }

    if (blockIdx.x == 0 && t == 0) {
        float emb0[NBASIS];
        #pragma unroll
        for (int b = 0; b < NBASIS; ++b) emb0[b] = s_b2[b];
        for (int w = 0; w < WIDTH; ++w) {
            float h = fast_tanh(s_b1[w]);   // x = 0
            #pragma unroll
            for (int b = 0; b < NBASIS; ++b)
                emb0[b] = fmaf(h, s_w2[w * NBASIS + b], emb0[b]);
        }
        #pragma unroll
        for (int b = 0; b < NBASIS; ++b) {
            float lc = fmaxf(log_cosh_f(emb0[b]), 0.0f);
            hegf[b] = lc * sqrtf(lc);       // lc^1.5
        }
    }
}

// ---------------- Stage 2: all-pairs, 2 i's/wave, hybrid exp ----------
// wave w owns i0=2w, i1=2w+1; lane L handles j = 64k+L. q=0,1 use hw
// v_exp_f32 (trans pipe); q=2,3 use packed poly exp2 (VALU pipe) so the
// two pipes overlap. Butterfly-reduce, lane 0 stores with heg fused.
__global__ __launch_bounds__(256, 4)
void cg_pairs(const float* __restrict__ oc,
              const float4* __restrict__ cw,
              const float4* __restrict__ bnq,
              const float* __restrict__ hegf,
              float* __restrict__ out)
{
    int wave = (blockIdx.x << 2) | (threadIdx.x >> 6);
    int lane = threadIdx.x & 63;
    int i0 = wave << 1;
    int i1 = i0 | 1;

    v2f oxv = { oc[i0 * 3 + 0], oc[i1 * 3 + 0] };
    v2f oyv = { oc[i0 * 3 + 1], oc[i1 * 3 + 1] };
    v2f ozv = { oc[i0 * 3 + 2], oc[i1 * 3 + 2] };

    v2f acc[NBASIS];
    #pragma unroll
    for (int b = 0; b < NBASIS; ++b) acc[b] = (v2f)0.0f;

    #pragma unroll 2
    for (int k = 0; k < N_PTS / 64; ++k) {
        int j = (k << 6) | lane;                 // lane-consecutive: coalesced
        float4 c = cw[j];
        v2f dx = oxv - c.x;
        v2f dy = oyv - c.y;
        v2f dz = ozv - c.z;
        v2f d2 = dx * dx + dy * dy + dz * dz;    // pk_mul + 2x pk_fma

        // q = 0,1 : hardware exp (trans pipe)
        #pragma unroll
        for (int q = 0; q < 2; ++q) {
            float4 b4 = bnq[q * N_PTS + j];
            v2f p0 = b4.x * d2;
            v2f p1 = b4.y * d2;
            v2f p2 = b4.z * d2;
            v2f p3 = b4.w * d2;
            v2f e0 = { exp2_hw(p0.x), exp2_hw(p0.y) };
            v2f e1 = { exp2_hw(p1.x), exp2_hw(p1.y) };
            v2f e2 = { exp2_hw(p2.x), exp2_hw(p2.y) };
            v2f e3 = { exp2_hw(p3.x), exp2_hw(p3.y) };
            acc[q * 4 + 0] += e0 * c.w;
            acc[q * 4 + 1] += e1 * c.w;
            acc[q * 4 + 2] += e2 * c.w;
            acc[q * 4 + 3] += e3 * c.w;
        }
        // q = 2,3 : packed polynomial exp (full-rate VALU pipe)
        #pragma unroll
        for (int q = 2; q < 4; ++q) {
            float4 b4 = bnq[q * N_PTS + j];
            v2f e0 = exp2_poly(b4.x * d2);
            v2f e1 = exp2_poly(b4.y * d2);
            v2f e2 = exp2_poly(b4.z * d2);
            v2f e3 = exp2_poly(b4.w * d2);
            acc[q * 4 + 0] += e0 * c.w;
            acc[q * 4 + 1] += e1 * c.w;
            acc[q * 4 + 2] += e2 * c.w;
            acc[q * 4 + 3] += e3 * c.w;
        }
    }

    // 6-step butterfly over 64 lanes, 16 v2f values
    #pragma unroll
    for (int m = 1; m < 64; m <<= 1) {
        #pragma unroll
        for (int b = 0; b < NBASIS; ++b) {
            v2f other = { __shfl_xor(acc[b].x, m, 64),
                          __shfl_xor(acc[b].y, m, 64) };
            acc[b] += other;
        }
    }

    if (lane == 0) {
        #pragma unroll
        for (int b = 0; b < NBASIS; ++b) {
            float h = hegf[b];                   // wave-uniform s_load
            out[i0 * NBASIS + b] = acc[b].x * h;
            out[i1 * NBASIS + b] = acc[b].y * h;
        }
    }
}

extern "C" void kernel_launch(void* const* d_in, const int* in_sizes, int n_in,
                              void* d_out, int out_size, void* d_ws, size_t ws_size,
                              hipStream_t stream) {
    const float* rho        = (const float*)d_in[0];
    const float* gamma      = (const float*)d_in[1];
    const float* coords     = (const float*)d_in[2];
    const float* weights    = (const float*)d_in[3];
    const float* out_coords = (const float*)d_in[4];
    const float* w1         = (const float*)d_in[5];
    const float* b1         = (const float*)d_in[6];
    const float* w2         = (const float*)d_in[7];
    const float* b2         = (const float*)d_in[8];

    char* ws = (char*)d_ws;
    // ws layout (640 KiB + 64 B):
    //   cw   : N * float4              = 128 KiB  @ 0
    //   bnq  : 4 planes * N * float4   = 512 KiB  @ 128K
    //   hegf : 16 * float                          @ 640K
    float4* cw   = (float4*)(ws);
    float4* bnq  = (float4*)(ws + (128 << 10));
    float*  hegf = (float*) (ws + (640 << 10));

    cg_prep<<<N_PTS / 64, 64, 0, stream>>>(rho, gamma, coords, weights,
                                           w1, b1, w2, b2,
                                           cw, bnq, hegf);

    cg_pairs<<<M_PTS / 8, 256, 0, stream>>>(out_coords, cw, bnq, hegf,
                                            (float*)d_out);
}

// Round 15
// 216.817 us; speedup vs baseline: 1.1708x; 1.1708x over previous
//
#include <hip/hip_runtime.h>
#include <hip/hip_bf16.h>

// CoarseGraining: y[i,b] = heg[b] * sum_j exp(-beta[j,b] * d2(i,j)) * wrho[j]
// N = M = 8192, NB = 16, WIDTH = 32. Inputs float32, output float32.
// R13 (2 i/wave, packed f32, hw exp): pairs 134us, busy 104us, occ 31%
// (grid-limited 4 waves/SIMD). R14 poly-exp hybrid REGRESSED (206us): v_exp
// ~12 issue-cyc has no cheaper VALU substitute; total issue cycles is the
// currency. R15: j-split x2 WITHOUT atomics — half0 stores raw partials to
// out, half1 to ypart (ws), combine kernel applies (out+ypart)*heg.
// 8192 waves -> 8/SIMD ceiling; clean TLP test (R12's atomic/memset
// confounds removed). ws = 1.1253 MB (exact R1-proven footprint).
// Builtins: exp2 = __builtin_amdgcn_exp2f, log2 = __builtin_amdgcn_logf.

#define N_PTS 8192
#define M_PTS 8192
#define NBASIS 16
#define WIDTH 32

typedef float v2f __attribute__((ext_vector_type(2)));

__device__ __forceinline__ float exp2_hw(float x) { return __builtin_amdgcn_exp2f(x); }
__device__ __forceinline__ float log2_hw(float x) { return __builtin_amdgcn_logf(x); }

__device__ __forceinline__ float fast_tanh(float z) {
    float a = fabsf(z);
    float t = __expf(-2.0f * a);
    float r = (1.0f - t) / (1.0f + t);
    return copysignf(r, z);
}

__device__ __forceinline__ float log_cosh_f(float x) {
    float a = fabsf(x);
    return a + __logf(1.0f + __expf(-2.0f * a)) - 0.6931471805599453f;
}

// ---------------- Stage 1: per-source-point quantities ----------------
// cw[j]        = (cx, cy, cz, wrho)
// bnq[q*N + j] = float4{ bn[j][4q..4q+3] }, bn = -log2(e)*beta (q-plane layout)
// hegf[0..15]  = log_cosh(embed(0))^1.5
__global__ __launch_bounds__(64)
void cg_prep(const float* __restrict__ rho,
             const float* __restrict__ gamma,
             const float* __restrict__ coords,
             const float* __restrict__ weights,
             const float* __restrict__ w1,
             const float* __restrict__ b1,
             const float* __restrict__ w2,
             const float* __restrict__ b2,
             float4* __restrict__ cw,
             float4* __restrict__ bnq,
             float* __restrict__ hegf)
{
    const float PI_F = 3.14159265358979323846f;
    const float LOG2E = 1.4426950408889634f;

    __shared__ float s_w1[WIDTH], s_b1[WIDTH], s_w2[WIDTH * NBASIS], s_b2[NBASIS];
    int t = threadIdx.x;
    if (t < WIDTH) { s_w1[t] = w1[t]; s_b1[t] = b1[t]; }
    if (t < NBASIS) s_b2[t] = b2[t];
    #pragma unroll
    for (int k = 0; k < 8; ++k) s_w2[t + 64 * k] = w2[t + 64 * k];
    __syncthreads();

    int j = blockIdx.x * 64 + t;
    {
        float r = rho[j];
        float g = gamma[j];
        const float c83 = 38.28312007948569f;              // 4*(3*pi^2)^(2/3)
        float r83 = exp2_hw(2.6666666667f * log2_hw(r));   // r^(8/3)
        float s2 = g / (c83 * r83);
        float x = __logf(s2 + 1e-4f);

        float emb[NBASIS];
        #pragma unroll
        for (int b = 0; b < NBASIS; ++b) emb[b] = s_b2[b];
        #pragma unroll 4
        for (int w = 0; w < WIDTH; ++w) {
            float h = fast_tanh(fmaf(x, s_w1[w], s_b1[w]));
            #pragma unroll
            for (int b = 0; b < NBASIS; ++b)
                emb[b] = fmaf(h, s_w2[w * NBASIS + b], emb[b]);
        }
        float pref = PI_F * exp2_hw(0.6666666667f * log2_hw(0.5f * r));
        float scale = -LOG2E * pref;
        #pragma unroll
        for (int q = 0; q < 4; ++q) {
            bnq[q * N_PTS + j] = make_float4(scale * log_cosh_f(emb[4 * q + 0]),
                                             scale * log_cosh_f(emb[4 * q + 1]),
                                             scale * log_cosh_f(emb[4 * q + 2]),
                                             scale * log_cosh_f(emb[4 * q + 3]));
        }

        cw[j] = make_float4(coords[j * 3 + 0],
                            coords[j * 3 + 1],
                            coords[j * 3 + 2],
                            weights[j] * r);
    }

    if (blockIdx.x == 0 && t == 0) {
        float emb0[NBASIS];
        #pragma unroll
        for (int b = 0; b < NBASIS; ++b) emb0[b] = s_b2[b];
        for (int w = 0; w < WIDTH; ++w) {
            float h = fast_tanh(s_b1[w]);   // x = 0
            #pragma unroll
            for (int b = 0; b < NBASIS; ++b)
                emb0[b] = fmaf(h, s_w2[w * NBASIS + b], emb0[b]);
        }
        #pragma unroll
        for (int b = 0; b < NBASIS; ++b) {
            float lc = fmaxf(log_cosh_f(emb0[b]), 0.0f);
            hegf[b] = lc * sqrtf(lc);       // lc^1.5
        }
    }
}

// ---------------- Stage 2: all-pairs, 2 i's/wave, j-split x2 ----------
// 2048 blocks x 4 waves = 8192 waves. wid in [0,8192): half = wid>>12,
// pair = wid & 4095; i0=2*pair, i1=i0+1; j in [half*4096, +4096).
// Blocks 0-1023 are all half0 (stream j-low 320KB), 1024-2047 half1.
// half0 stores raw partial to out; half1 to ypart. No atomics.
__global__ __launch_bounds__(256, 8)
void cg_pairs(const float* __restrict__ oc,
              const float4* __restrict__ cw,
              const float4* __restrict__ bnq,
              float* __restrict__ out,
              float* __restrict__ ypart)
{
    int wid  = (blockIdx.x << 2) | (threadIdx.x >> 6);   // 0..8191
    int lane = threadIdx.x & 63;
    int half = wid >> 12;                                 // 0 or 1
    int pair = wid & 4095;
    int i0 = pair << 1;
    int i1 = i0 | 1;
    int jbase = half << 12;                               // 0 or 4096

    v2f oxv = { oc[i0 * 3 + 0], oc[i1 * 3 + 0] };
    v2f oyv = { oc[i0 * 3 + 1], oc[i1 * 3 + 1] };
    v2f ozv = { oc[i0 * 3 + 2], oc[i1 * 3 + 2] };

    v2f acc[NBASIS];
    #pragma unroll
    for (int b = 0; b < NBASIS; ++b) acc[b] = (v2f)0.0f;

    #pragma unroll 2
    for (int k = 0; k < 64; ++k) {
        int j = jbase + (k << 6) + lane;         // lane-consecutive: coalesced
        float4 c = cw[j];
        v2f dx = oxv - c.x;
        v2f dy = oyv - c.y;
        v2f dz = ozv - c.z;
        v2f d2 = dx * dx + dy * dy + dz * dz;    // pk_mul + 2x pk_fma
        #pragma unroll
        for (int q = 0; q < 4; ++q) {
            float4 b4 = bnq[q * N_PTS + j];      // coalesced dwordx4
            v2f p0 = b4.x * d2;                  // pk_mul
            v2f p1 = b4.y * d2;
            v2f p2 = b4.z * d2;
            v2f p3 = b4.w * d2;
            v2f e0 = { exp2_hw(p0.x), exp2_hw(p0.y) };
            v2f e1 = { exp2_hw(p1.x), exp2_hw(p1.y) };
            v2f e2 = { exp2_hw(p2.x), exp2_hw(p2.y) };
            v2f e3 = { exp2_hw(p3.x), exp2_hw(p3.y) };
            acc[q * 4 + 0] += e0 * c.w;          // pk_fma
            acc[q * 4 + 1] += e1 * c.w;
            acc[q * 4 + 2] += e2 * c.w;
            acc[q * 4 + 3] += e3 * c.w;
        }
    }

    // 6-step butterfly over 64 lanes, 16 v2f values
    #pragma unroll
    for (int m = 1; m < 64; m <<= 1) {
        #pragma unroll
        for (int b = 0; b < NBASIS; ++b) {
            v2f other = { __shfl_xor(acc[b].x, m, 64),
                          __shfl_xor(acc[b].y, m, 64) };
            acc[b] += other;
        }
    }

    if (lane == 0) {
        float* dst = half ? ypart : out;
        #pragma unroll
        for (int b = 0; b < NBASIS; ++b) {
            dst[i0 * NBASIS + b] = acc[b].x;     // raw partial (heg in combine)
            dst[i1 * NBASIS + b] = acc[b].y;
        }
    }
}

// ---------------- Stage 3: combine halves + heg scale ----------------
__global__ __launch_bounds__(256)
void cg_combine(float* __restrict__ out,
                const float* __restrict__ ypart,
                const float* __restrict__ hegf)
{
    int idx = blockIdx.x * blockDim.x + threadIdx.x;     // [0, M*NB)
    out[idx] = (out[idx] + ypart[idx]) * hegf[idx & (NBASIS - 1)];
}

extern "C" void kernel_launch(void* const* d_in, const int* in_sizes, int n_in,
                              void* d_out, int out_size, void* d_ws, size_t ws_size,
                              hipStream_t stream) {
    const float* rho        = (const float*)d_in[0];
    const float* gamma      = (const float*)d_in[1];
    const float* coords     = (const float*)d_in[2];
    const float* weights    = (const float*)d_in[3];
    const float* out_coords = (const float*)d_in[4];
    const float* w1         = (const float*)d_in[5];
    const float* b1         = (const float*)d_in[6];
    const float* w2         = (const float*)d_in[7];
    const float* b2         = (const float*)d_in[8];

    char* ws = (char*)d_ws;
    // ws layout (1,179,712 B = 1.1253 MB — exact R1-proven footprint):
    //   cw    : N * float4             = 128 KiB  @ 0
    //   bnq   : 4 planes * N * float4  = 512 KiB  @ 128K
    //   ypart : M * 16 * float         = 512 KiB  @ 640K
    //   hegf  : 16 * float (64 B)                 @ 1152K
    float4* cw    = (float4*)(ws);
    float4* bnq   = (float4*)(ws + (128 << 10));
    float*  ypart = (float*) (ws + (640 << 10));
    float*  hegf  = (float*) (ws + (1152 << 10));

    cg_prep<<<N_PTS / 64, 64, 0, stream>>>(rho, gamma, coords, weights,
                                           w1, b1, w2, b2,
                                           cw, bnq, hegf);

    cg_pairs<<<M_PTS / 4, 256, 0, stream>>>(out_coords, cw, bnq,
                                            (float*)d_out, ypart);

    cg_combine<<<(M_PTS * NBASIS) / 256, 256, 0, stream>>>((float*)d_out,
                                                           ypart, hegf);
}